// Round 9
// baseline (230.575 us; speedup 1.0000x reference)
//
#include <hip/hip_runtime.h>

constexpr int BATCH = 2048;
constexpr int NHID  = 512;
constexpr int H0    = 256;
constexpr int H1    = 256;
constexpr int S     = 8;     // samples per tile (short per-wave critical path)
constexpr int J     = 3;     // tile-slot blocks per parent (grid = 256*J)
constexpr int KSL   = 128;   // K-rows per wave chunk (4-way K-split per pass)

// Block (p, j): 512 thr = 8 waves. Waves 0-3 bottom pass, 4-7 top pass;
// wave's kq = g&3 streams W rows [128*kq, +128) for THIS tile's 8 samples
// with r0's verified 8-float4 register ring. K-partials reduced via LDS
// (r1's verified path, absmax 0.0), wave kq==0 of each pass runs the
// shuffle softmax; combine in-block.
// Rationale (r0-r8 evidence): per-wave streams are exposed-latency bound at
// <=2 waves/SIMD; this shape keeps r0's short h-step AND supplies ~2.5-4
// live waves/SIMD (768 blocks, 2 blocks/CU by LDS, VGPR ~110 < 128 cap).
__global__ __launch_bounds__(512) void hs_v6(
    const float* __restrict__ x,        // [B, NHID]
    const int*   __restrict__ labels,   // [B]
    const int*   __restrict__ parents,  // [B]
    const float* __restrict__ topW,     // [NHID, H0]
    const float* __restrict__ topb,     // [H0]
    const float* __restrict__ botW,     // [H0, NHID, H1]
    const float* __restrict__ botb,     // [H0, H1]
    float*       __restrict__ out)      // [B]
{
    const int p  = blockIdx.x / J;
    const int j  = blockIdx.x % J;
    const int t  = threadIdx.x;        // 0..511
    const int g  = t >> 6;             // wave 0..7
    const int l  = t & 63;
    const int kq = g & 3;              // K-chunk index within pass
    const bool bot = (g < 4);
    const int pi = bot ? 0 : 1;        // red page
    const int po = bot ? 1 : 0;        // psm page (psm[0]=top, psm[1]=bottom)

    __shared__ int list[BATCH];                       // 8 KB
    __shared__ int wcnt[8];
    __shared__ __align__(16) float  xs[S][NHID];      // 16 KB
    __shared__ __align__(16) float4 red[2][3][S][64]; // 48 KB
    __shared__ float psm[2][S];                       // ~74 KB total

    // ---- deterministic list build (r1-verified 512-thr ballot scan)
    int running = 0;
    for (int c = 0; c < BATCH; c += 512) {
        const bool match = (parents[c + t] == p);
        const unsigned long long mask = __ballot(match);
        if (l == 0) wcnt[g] = __popcll(mask);
        __syncthreads();
        int off = running;
        #pragma unroll
        for (int w = 0; w < 8; ++w) {
            const int cw = wcnt[w];
            if (w < g) off += cw;
            running += cw;
        }
        if (match)
            list[off + __popcll(mask & ((1ull << l) - 1ull))] = c + t;
        __syncthreads();   // wcnt reused next chunk
    }
    const int n = running;
    if (n <= j * S) return;   // block-uniform exit (before tile barriers)

    const float* Wbase = bot
        ? botW + (size_t)p * NHID * H1 + (size_t)kq * KSL * H1
        : topW + (size_t)kq * KSL * H0;
    const float4 b4 = bot ? *(const float4*)(botb + (size_t)p * H1 + 4 * l)
                          : *(const float4*)(topb + 4 * l);
    const int xoff = kq * KSL;

    for (int base = j * S; base < n; base += J * S) {   // ~always 1 iter
        const int rem = min(S, n - base);

        // ---- stage 8 x-rows: 512 thr stage 4 rows/iter, 2 iters
        #pragma unroll
        for (int s0 = 0; s0 < S; s0 += 4) {
            const int row = s0 + (t >> 7);
            const int idx = list[base + min(row, rem - 1)];
            ((float4*)xs[row])[t & 127] =
                ((const float4*)(x + (size_t)idx * NHID))[t & 127];
        }
        __syncthreads();   // xs ready

        // ---- K-chunk register GEMV: 8 samples, 4 cols/lane (r0 engine)
        float4 acc[S];
        #pragma unroll
        for (int s = 0; s < S; ++s) acc[s] = make_float4(0.f, 0.f, 0.f, 0.f);

        const float* Wp = Wbase + 4 * l;
        float4 ring[8];
        #pragma unroll
        for (int i = 0; i < 8; ++i)
            ring[i] = *(const float4*)(Wp + (size_t)i * 256);

        for (int d = 0; d < KSL; d += 8) {
            #pragma unroll
            for (int h = 0; h < 2; ++h) {
                const int dd = d + 4 * h;
                const float4 w0 = ring[4 * h + 0], w1 = ring[4 * h + 1];
                const float4 w2 = ring[4 * h + 2], w3 = ring[4 * h + 3];
                if (dd + 8 < KSL) {          // use-distance 2 h-steps
                    #pragma unroll
                    for (int i = 0; i < 4; ++i)
                        ring[4 * h + i] =
                            *(const float4*)(Wp + (size_t)(dd + 8 + i) * 256);
                }
                #pragma unroll
                for (int s = 0; s < S; ++s) {
                    const float4 xv = *(const float4*)&xs[s][xoff + dd];
                    float4 a = acc[s];
                    a.x = fmaf(xv.x, w0.x, a.x); a.y = fmaf(xv.x, w0.y, a.y);
                    a.z = fmaf(xv.x, w0.z, a.z); a.w = fmaf(xv.x, w0.w, a.w);
                    a.x = fmaf(xv.y, w1.x, a.x); a.y = fmaf(xv.y, w1.y, a.y);
                    a.z = fmaf(xv.y, w1.z, a.z); a.w = fmaf(xv.y, w1.w, a.w);
                    a.x = fmaf(xv.z, w2.x, a.x); a.y = fmaf(xv.z, w2.y, a.y);
                    a.z = fmaf(xv.z, w2.z, a.z); a.w = fmaf(xv.z, w2.w, a.w);
                    a.x = fmaf(xv.w, w3.x, a.x); a.y = fmaf(xv.w, w3.y, a.y);
                    a.z = fmaf(xv.w, w3.z, a.z); a.w = fmaf(xv.w, w3.w, a.w);
                    acc[s] = a;
                }
            }
        }

        // ---- cross-wave K-reduction (r1-verified order) + softmax
        if (kq != 0) {
            #pragma unroll
            for (int s = 0; s < S; ++s) red[pi][kq - 1][s][l] = acc[s];
        }
        __syncthreads();   // partials visible
        if (kq == 0) {
            #pragma unroll
            for (int s = 0; s < S; ++s) {
                const float4 r0 = red[pi][0][s][l];
                const float4 r1 = red[pi][1][s][l];
                const float4 r2 = red[pi][2][s][l];
                float4 v = acc[s];
                v.x += r0.x + r1.x + r2.x + b4.x;
                v.y += r0.y + r1.y + r2.y + b4.y;
                v.z += r0.z + r1.z + r2.z + b4.z;
                v.w += r0.w + r1.w + r2.w + b4.w;

                float m = fmaxf(fmaxf(v.x, v.y), fmaxf(v.z, v.w));
                #pragma unroll
                for (int off = 32; off > 0; off >>= 1)
                    m = fmaxf(m, __shfl_xor(m, off, 64));

                const float ex = expf(v.x - m), ey = expf(v.y - m);
                const float ez = expf(v.z - m), ew = expf(v.w - m);
                float sum = (ex + ey) + (ez + ew);
                #pragma unroll
                for (int off = 32; off > 0; off >>= 1)
                    sum += __shfl_xor(sum, off, 64);

                const int tgt = bot ? labels[list[base + min(s, rem - 1)]] : p;
                const int k   = tgt & 3;
                const float ev = (k == 0) ? ex : (k == 1) ? ey
                               : (k == 2) ? ez : ew;
                if (l == (tgt >> 2))
                    psm[po][s] = ev / sum;
            }
        }
        __syncthreads();   // psm complete / red reusable

        if (t < rem) {
            const int idx = list[base + t];
            out[idx] = psm[0][t] * psm[1][t];
        }
        __syncthreads();   // xs/psm safe to overwrite next tile
    }
}

extern "C" void kernel_launch(void* const* d_in, const int* in_sizes, int n_in,
                              void* d_out, int out_size, void* d_ws, size_t ws_size,
                              hipStream_t stream) {
    const float* x       = (const float*)d_in[0];
    const int*   labels  = (const int*)  d_in[1];
    const int*   parents = (const int*)  d_in[2];
    const float* topW    = (const float*)d_in[3];
    const float* topb    = (const float*)d_in[4];
    const float* botW    = (const float*)d_in[5];
    const float* botb    = (const float*)d_in[6];
    float*       out     = (float*)d_out;

    hs_v6<<<H0 * J, 512, 0, stream>>>(x, labels, parents,
                                      topW, topb, botW, botb, out);
}